// Round 6
// baseline (147.317 us; speedup 1.0000x reference)
//
#include <hip/hip_runtime.h>

typedef unsigned short u16;
typedef unsigned int   u32;
typedef __attribute__((ext_vector_type(8))) short short8;   // 8 x bf16 (4 VGPRs)
typedef __attribute__((ext_vector_type(16))) float f32x16;

#define MFMA32(a, b, c) __builtin_amdgcn_mfma_f32_32x32x16_bf16(a, b, c, 0, 0, 0)

constexpr int Lv = 2048, Hv = 8, Ev = 64, HE = Hv * Ev; // HE=512
constexpr float QSCALE = 0.18033688011112042f;          // 0.125 * log2(e)

__device__ __forceinline__ float bf2f(u16 u) {
    u32 x = ((u32)u) << 16;
    return __builtin_bit_cast(float, x);
}
__device__ __forceinline__ u16 f2bf(float f) {   // RNE, finite inputs
    u32 x = __builtin_bit_cast(u32, f);
    u32 r = ((x >> 16) & 1u) + 0x7fffu;
    return (u16)((x + r) >> 16);
}
// packed f32x2 -> bf16x2 (low = a, high = b), RNE
__device__ __forceinline__ u32 pkbf(float a, float b) {
#if __has_builtin(__builtin_amdgcn_cvt_pk_bf16_f32)
    typedef __attribute__((ext_vector_type(2))) __bf16 bf16x2;
    bf16x2 v = __builtin_amdgcn_cvt_pk_bf16_f32(a, b);
    return __builtin_bit_cast(u32, v);
#else
    return (u32)f2bf(a) | ((u32)f2bf(b) << 16);
#endif
}
__device__ __forceinline__ float fexp2(float x) {
#if __has_builtin(__builtin_amdgcn_exp2f)
    return __builtin_amdgcn_exp2f(x);
#else
    return exp2f(x);
#endif
}

// Runtime dtype sniff (validated: fp32 inputs detected correctly).
__device__ __forceinline__ int detect_isbf16(const u32* q32, int lane) {
    u32 w0 = q32[2 * lane];
    u32 w1 = q32[2 * lane + 1];
    u16 uu[4] = { (u16)(w0 & 0xffff), (u16)(w0 >> 16),
                  (u16)(w1 & 0xffff), (u16)(w1 >> 16) };
    int p = 0, z = 0;
#pragma unroll
    for (int j = 0; j < 4; ++j) {
        u16 mgn = (u16)(uu[j] & 0x7fff);
        int ex  = mgn >> 7;
        bool zero = (mgn == 0);
        bool pl   = zero || (ex >= 115 && ex <= 132);
        p += pl ? 1 : 0;
        if ((j & 1) == 0) z += zero ? 1 : 0;
    }
    int acc = p | (z << 16);
#pragma unroll
    for (int o = 1; o < 64; o <<= 1) acc += __shfl_xor(acc, o);
    int ps = acc & 0xffff, zs = acc >> 16;
    if (zs >= 100) return 0;
    return (ps >= 240) ? 1 : 0;
}

__device__ __forceinline__ short8 cvt8s(const float* p, float s) {
    float4 a = *(const float4*)p, b4 = *(const float4*)(p + 4);
    u32 r[4] = { pkbf(a.x * s, a.y * s), pkbf(a.z * s, a.w * s),
                 pkbf(b4.x * s, b4.y * s), pkbf(b4.z * s, b4.w * s) };
    return *(short8*)r;
}

__device__ __forceinline__ f32x16 zv16() {
    f32x16 z;
#pragma unroll
    for (int r = 0; r < 16; ++r) z[r] = 0.f;
    return z;
}

// Exchange a.hi-lanes <-> b.lo-lanes (v_permlane32_swap_b32 semantics).
__device__ __forceinline__ void plswap(u32& a, u32& b) {
#if __has_builtin(__builtin_amdgcn_permlane32_swap)
    auto r = __builtin_amdgcn_permlane32_swap(a, b, false, false);
    a = r[0]; b = r[1];
#else
    int lane = (int)(threadIdx.x & 63);
    u32 ax = (u32)__shfl_xor((int)a, 32);
    u32 bx = (u32)__shfl_xor((int)b, 32);
    bool hi = lane >= 32;
    u32 na = hi ? bx : a;
    u32 nb = hi ? b  : ax;
    a = na; b = nb;
#endif
}

// ---------------------------------------------------------------------------
// Fused full attention + l=0 local blend.
// Round-6 = round-3 geometry (512 blocks x 512 thr, 128 q/block, KVBLK=64
// shared double-buffered K/V tile, 32 iterations, single prefetch set -> no
// spill) with the VALU stream slimmed:
//   * row sums on the MFMA pipe: Ssum = MFMA(pa, ones, Ssum) (2/kt). The
//     32x32 D-layout row (reg&3)+8*(reg>>2)+4*hi aligns Ssum[reg] exactly
//     with O[et][reg]'s query row -> epilogue needs NO cross-lane ops.
//   * in-place exp2 on St (no pe[16] transient) -> frees the VGPRs that the
//     Ssum accumulator costs; net register-neutral vs round 3.
//   * s_setprio(1) around MFMA clusters (only clean R5 delta).
// Wave w = (qg = w&3: 32-query sub-block) x (g = w>>2: key-half of tile).
// Split-K halves combined through LDS at the end (exact, unnormalized).
// ---------------------------------------------------------------------------
template <int ISBF>
__device__ __forceinline__ void attn_impl(
    const void* __restrict__ qv, const void* __restrict__ kv,
    const void* __restrict__ vv, const void* __restrict__ alphav,
    void* __restrict__ outv, u16* SMEM)
{
    const int tid  = threadIdx.x;       // 0..511
    const int w    = tid >> 6;          // wave 0..7
    const int lane = tid & 63;
    const int l31  = lane & 31;
    const int hi   = lane >> 5;
    const int qg   = w & 3;             // query sub-block (32 rows)
    const int g    = w >> 2;            // key-half of each 64-key tile

    // XCD-aware mapping: xcd = fid&7 handles bh in {4*xcd .. 4*xcd+3}.
    const int fid = blockIdx.x;         // 0..511
    const int bh  = (fid & 7) * 4 + ((fid >> 3) & 3);
    const int rb  = fid >> 5;           // 0..15
    const int b   = bh >> 3, h = bh & 7;
    const int row0 = rb * 128;

    const size_t bhoff = (size_t)b * Lv * HE + h * Ev;
    const u16*   q16 = (const u16*)qv + bhoff;
    const u16*   k16 = (const u16*)kv + bhoff;
    const u16*   v16 = (const u16*)vv + bhoff;
    const float* q32 = (const float*)qv + bhoff;
    const float* k32 = (const float*)kv + bhoff;
    const float* v32 = (const float*)vv + bhoff;

    u16* Klds = SMEM;            // 2 bufs x 4096 u16  [key 0..63][e], swizzled
    u16* Vt   = SMEM + 8192;     // 2 bufs x 4096 u16  [e][key 0..63], swizzled

    // Q fragments (pre-scaled). B-operand of the 32x32 S^T MFMA:
    // qf[c][j] = Qs[row0+qg*32+l31][16c + 8hi + j].
    short8 qf[4];
    {
        size_t ro = (size_t)(row0 + qg * 32 + l31) * HE + hi * 8;
        if (ISBF) {
#pragma unroll
            for (int c = 0; c < 4; ++c) {
                short8 t = *(const short8*)(q16 + ro + 16 * c);
#pragma unroll
                for (int j = 0; j < 8; ++j)
                    qf[c][j] = (short)f2bf(bf2f((u16)t[j]) * QSCALE);
            }
        } else {
#pragma unroll
            for (int c = 0; c < 4; ++c) qf[c] = cvt8s(q32 + ro + 16 * c, QSCALE);
        }
    }

    short8 ones8;
#pragma unroll
    for (int j = 0; j < 8; ++j) ones8[j] = (short)0x3F80;   // bf16 1.0

    f32x16 O[2];
    O[0] = zv16(); O[1] = zv16();
    f32x16 Ssum = zv16();   // row sums via MFMA; Ssum[reg] = denom of row rl(reg,hi)

    // K staging (512 threads, one 64-key tile): chunk tid: key=tid>>3,
    // slot=tid&7; XOR swizzle folded into GLOBAL offset, LDS write linear.
    const int kkey = tid >> 3, ksl = tid & 7;
    const int koff = kkey * HE + ((ksl ^ (kkey & 7)) * 8);
    // V staging: key-pair (2*pp, 2*pp+1), e-quad eq (4 e values).
    const int eq = tid & 15, pp = tid >> 4;      // pp 0..31
    const int kcv = pp >> 2, pq = pp & 3;

    // ---- prefetch registers (single set: proven no-spill in round 3) ----
    float4 kfa, kfb, vfa, vfb;          // fp32 path
    uint4  kru; uint2 vru0, vru1;       // bf16 path

#define LOAD_TILE(KT)                                                          \
    do {                                                                       \
        size_t kb_ = (size_t)(KT) * 64 * HE;                                   \
        if (ISBF) {                                                            \
            kru  = *(const uint4*)(k16 + kb_ + koff);                          \
            const u16* vp_ = v16 + kb_ + (size_t)(2 * pp) * HE + eq * 4;       \
            vru0 = *(const uint2*)vp_;                                         \
            vru1 = *(const uint2*)(vp_ + HE);                                  \
        } else {                                                               \
            const float* kp_ = k32 + kb_ + koff;                               \
            kfa = *(const float4*)kp_;                                         \
            kfb = *(const float4*)(kp_ + 4);                                   \
            const float* vp_ = v32 + kb_ + (size_t)(2 * pp) * HE + eq * 4;     \
            vfa = *(const float4*)vp_;                                         \
            vfb = *(const float4*)(vp_ + HE);                                  \
        }                                                                      \
    } while (0)

#define STORE_TILE(KB, VB)                                                     \
    do {                                                                       \
        if (ISBF) {                                                            \
            *(uint4*)&(KB)[tid * 8] = kru;                                     \
            const u16* a0_ = (const u16*)&vru0;                                \
            const u16* a1_ = (const u16*)&vru1;                                \
            _Pragma("unroll")                                                  \
            for (int j = 0; j < 4; ++j) {                                      \
                int e_  = eq * 4 + j;                                          \
                int sl_ = kcv ^ ((e_ + (e_ >> 3)) & 7);                        \
                u32 val_ = (u32)a0_[j] | ((u32)a1_[j] << 16);                  \
                *(u32*)&(VB)[e_ * 64 + sl_ * 8 + pq * 2] = val_;               \
            }                                                                  \
        } else {                                                               \
            u32 kk_[4] = { pkbf(kfa.x, kfa.y), pkbf(kfa.z, kfa.w),             \
                           pkbf(kfb.x, kfb.y), pkbf(kfb.z, kfb.w) };           \
            *(uint4*)&(KB)[tid * 8] = *(uint4*)kk_;                            \
            float t0_[4] = {vfa.x, vfa.y, vfa.z, vfa.w};                       \
            float t1_[4] = {vfb.x, vfb.y, vfb.z, vfb.w};                       \
            _Pragma("unroll")                                                  \
            for (int j = 0; j < 4; ++j) {                                      \
                int e_  = eq * 4 + j;                                          \
                int sl_ = kcv ^ ((e_ + (e_ >> 3)) & 7);                        \
                *(u32*)&(VB)[e_ * 64 + sl_ * 8 + pq * 2] = pkbf(t0_[j], t1_[j]);\
            }                                                                  \
        }                                                                      \
    } while (0)

    // ---- prologue: stage tile 0 into buffer 0 ----
    LOAD_TILE(0);
    STORE_TILE(Klds, Vt);
    __syncthreads();

    for (int kt = 0; kt < 32; ++kt) {
        u16* Kb = Klds + (kt & 1) * 4096;
        u16* Vb = Vt   + (kt & 1) * 4096;
        u16* Kn = Klds + ((kt & 1) ^ 1) * 4096;
        u16* Vn = Vt   + ((kt & 1) ^ 1) * 4096;

        if (kt < 31) LOAD_TILE(kt + 1);   // in flight across all compute below

        // ---- S^T = K (Q*c)^T for THIS WAVE'S 32-key half (keys g*32+..) ----
        // D: col = query = l31, row = local key = (reg&3)+8*(reg>>2)+4*hi.
        f32x16 St = zv16();
        __builtin_amdgcn_s_setprio(1);
#pragma unroll
        for (int c = 0; c < 4; ++c) {
            int sl = (2 * c + hi) ^ (l31 & 7);   // (krow&7) == (l31&7)
            short8 kf = *(const short8*)&Kb[(g * 32 + l31) * 64 + sl * 8];
            St = MFMA32(kf, qf[c], St);
        }
        __builtin_amdgcn_s_setprio(0);

        // ---- P = exp2(St) IN PLACE; transpose to A-operand in registers ----
#pragma unroll
        for (int r = 0; r < 16; ++r) St[r] = fexp2(St[r]);
        u32 c8[8];
#pragma unroll
        for (int q = 0; q < 8; ++q) c8[q] = pkbf(St[2 * q], St[2 * q + 1]);
#pragma unroll
        for (int t = 0; t < 2; ++t) {
            // A-operand for tile-kstep ks = 2g+t: keys 16ks + 8hi + {0..7}.
            u32 a0 = c8[4 * t + 0], a1 = c8[4 * t + 1];
            u32 a2 = c8[4 * t + 2], a3 = c8[4 * t + 3];
            plswap(a0, a2);
            plswap(a1, a3);
            u32 pw_[4] = { a0, a1, a2, a3 };
            short8 pa = *(short8*)pw_;
            int ks = 2 * g + t;
            __builtin_amdgcn_s_setprio(1);
            Ssum = MFMA32(pa, ones8, Ssum);   // row sums on the MFMA pipe
#pragma unroll
            for (int et = 0; et < 2; ++et) {
                int e  = et * 32 + l31;
                int sl = (2 * ks + hi) ^ ((e + (e >> 3)) & 7);
                short8 vf = *(const short8*)&Vb[e * 64 + sl * 8];
                O[et] = MFMA32(pa, vf, O[et]);
            }
            __builtin_amdgcn_s_setprio(0);
        }

        if (kt < 31) {
            STORE_TILE(Kn, Vn);   // buffer last read in iter kt-1; safe
            __syncthreads();
        }
    }
#undef LOAD_TILE
#undef STORE_TILE

    // ---- combine the two key-halves through LDS (exact, unnormalized) ----
    __syncthreads();                              // all K/V tile reads done
    float* cb = (float*)SMEM;                     // tiles dead; reuse as f32
    const int cbase = qg * 2368 + lane * 36;      // 36 f32 stride: 16B-aligned

    if (g == 1) {
        union { f32x16 v; float4 q4[4]; } u;
        u.v = O[0];
#pragma unroll
        for (int i = 0; i < 4; ++i) *(float4*)&cb[cbase + 4 * i] = u.q4[i];
        u.v = O[1];
#pragma unroll
        for (int i = 0; i < 4; ++i) *(float4*)&cb[cbase + 16 + 4 * i] = u.q4[i];
        // row-sum partials: Ssum[reg] is lane-uniform per hi-half; two lanes
        // (l31==0 of each half) cover all 32 rows of this qg.
        if (l31 == 0) {
#pragma unroll
            for (int reg = 0; reg < 16; ++reg) {
                int rl = (reg & 3) + 8 * (reg >> 2) + 4 * hi;
                cb[qg * 2368 + 2304 + rl] = Ssum[reg];
            }
        }
    }

    // ---- l=0 local attention (wave 0 = qg0/g0 of rb==0 blocks) ----
    float locv[2] = {0.f, 0.f};
    float wgt = 0.f;
    const bool w0blk = (rb == 0) && (w == 0);
    if (w0blk) {
        const int e = lane;
        const size_t base = bhoff + e;
#define LDIN(p, i) (ISBF ? bf2f(((const u16*)(p))[i]) : ((const float*)(p))[i])
        float qe = LDIN(qv, base);
        float s[9];
#pragma unroll
        for (int j = 0; j < 9; ++j) {
            float prod = qe * LDIN(kv, base + (size_t)j * HE);
#pragma unroll
            for (int o = 1; o < 64; o <<= 1) prod += __shfl_xor(prod, o);
            s[j] = prod * 0.125f;
        }
        float mx = s[0];
#pragma unroll
        for (int j = 1; j < 9; ++j) mx = fmaxf(mx, s[j]);
        float we[9];
#pragma unroll
        for (int j = 0; j < 9; ++j) we[j] = expf(s[j] - mx);
        float denom = 9.f * we[0];
        float acc   = 9.f * we[0] * LDIN(vv, base);
#pragma unroll
        for (int j = 1; j < 9; ++j) {
            denom += we[j];
            acc   += we[j] * LDIN(vv, base + (size_t)j * HE);
        }
        float loc = acc / denom;

        float a;
        if (ISBF) {
            a = bf2f(((const u16*)alphav)[0]);
            if (!(a >= 0.0f && a <= 1.0f)) {
                float af = ((const float*)alphav)[0];
                if (af >= 0.0f && af <= 1.0f) a = af;
            }
        } else {
            a = ((const float*)alphav)[0];
            if (!(a >= 0.0f && a <= 1.0f)) {
                float ab = bf2f(((const u16*)alphav)[0]);
                if (ab >= 0.0f && ab <= 1.0f) a = ab;
            }
        }
        wgt = 1.f / (1.f + expf(-a));
#pragma unroll
        for (int et = 0; et < 2; ++et) locv[et] = __shfl(loc, et * 32 + l31);
#undef LDIN
    }

    __syncthreads();                              // partials visible
    if (g != 0) return;

    // ---- g==0 waves: add partner partials, normalize, blend, store ----
#pragma unroll
    for (int r = 0; r < 16; ++r) {
        O[0][r] += cb[cbase + r];
        O[1][r] += cb[cbase + 16 + r];
    }

#pragma unroll
    for (int rg = 0; rg < 4; ++rg) {
#pragma unroll
        for (int rr = 0; rr < 4; ++rr) {
            const int reg = rg * 4 + rr;
            const int rl  = rr + 8 * rg + 4 * hi;       // local output row
            float pstp = cb[qg * 2368 + 2304 + rl];     // partner row sum
            float inv  = 1.0f / (Ssum[reg] + pstp);     // aligned with O[.][reg]
            int row = row0 + qg * 32 + rl;
            size_t oo = (size_t)(b * Lv + row) * HE + h * Ev + l31;
            bool blend = w0blk && (rl == 0);
#pragma unroll
            for (int et = 0; et < 2; ++et) {
                float res = O[et][reg] * inv;
                if (blend) res = wgt * res + (1.f - wgt) * locv[et];
                if (ISBF) ((u16*)outv)[oo + et * 32] = f2bf(res);
                else      ((float*)outv)[oo + et * 32] = res;
            }
        }
    }
}

__global__ __launch_bounds__(512, 4) void attn_kernel(
    const void* __restrict__ qv, const void* __restrict__ kv,
    const void* __restrict__ vv, const void* __restrict__ alphav,
    void* __restrict__ outv)
{
    // [0,8K) u16: K tiles (2 bufs x 64x64). [8K,16K) u16: V tiles (2 bufs).
    // Whole buffer reused as float scratch (9472 f32) for split-K combine;
    // per-qg layout: [0,2304) O partials, [2304,2336) row-sum partials.
    __shared__ u16 SMEM[18944];

    const int isbf = detect_isbf16((const u32*)qv, threadIdx.x & 63);
    if (isbf) attn_impl<1>(qv, kv, vv, alphav, outv, SMEM);
    else      attn_impl<0>(qv, kv, vv, alphav, outv, SMEM);
}

extern "C" void kernel_launch(void* const* d_in, const int* in_sizes, int n_in,
                              void* d_out, int out_size, void* d_ws, size_t ws_size,
                              hipStream_t stream) {
    hipLaunchKernelGGL(attn_kernel, dim3(512), dim3(512), 0, stream,
                       d_in[0], d_in[1], d_in[2], d_in[3], d_out);
}

// Round 8
// 143.247 us; speedup vs baseline: 1.0284x; 1.0284x over previous
//
#include <hip/hip_runtime.h>

typedef unsigned short u16;
typedef unsigned int   u32;
typedef __attribute__((ext_vector_type(8))) short short8;   // 8 x bf16 (4 VGPRs)
typedef __attribute__((ext_vector_type(16))) float f32x16;

#define MFMA32(a, b, c) __builtin_amdgcn_mfma_f32_32x32x16_bf16(a, b, c, 0, 0, 0)

constexpr int Lv = 2048, Hv = 8, Ev = 64, HE = Hv * Ev; // HE=512
constexpr float QSCALE = 0.18033688011112042f;          // 0.125 * log2(e)

__device__ __forceinline__ float bf2f(u16 u) {
    u32 x = ((u32)u) << 16;
    return __builtin_bit_cast(float, x);
}
__device__ __forceinline__ u16 f2bf(float f) {   // RNE, finite inputs
    u32 x = __builtin_bit_cast(u32, f);
    u32 r = ((x >> 16) & 1u) + 0x7fffu;
    return (u16)((x + r) >> 16);
}
// packed f32x2 -> bf16x2 (low = a, high = b), RNE
__device__ __forceinline__ u32 pkbf(float a, float b) {
#if __has_builtin(__builtin_amdgcn_cvt_pk_bf16_f32)
    typedef __attribute__((ext_vector_type(2))) __bf16 bf16x2;
    bf16x2 v = __builtin_amdgcn_cvt_pk_bf16_f32(a, b);
    return __builtin_bit_cast(u32, v);
#else
    return (u32)f2bf(a) | ((u32)f2bf(b) << 16);
#endif
}
__device__ __forceinline__ float fexp2(float x) {
#if __has_builtin(__builtin_amdgcn_exp2f)
    return __builtin_amdgcn_exp2f(x);
#else
    return exp2f(x);
#endif
}

// Runtime dtype sniff (validated: fp32 inputs detected correctly).
__device__ __forceinline__ int detect_isbf16(const u32* q32, int lane) {
    u32 w0 = q32[2 * lane];
    u32 w1 = q32[2 * lane + 1];
    u16 uu[4] = { (u16)(w0 & 0xffff), (u16)(w0 >> 16),
                  (u16)(w1 & 0xffff), (u16)(w1 >> 16) };
    int p = 0, z = 0;
#pragma unroll
    for (int j = 0; j < 4; ++j) {
        u16 mgn = (u16)(uu[j] & 0x7fff);
        int ex  = mgn >> 7;
        bool zero = (mgn == 0);
        bool pl   = zero || (ex >= 115 && ex <= 132);
        p += pl ? 1 : 0;
        if ((j & 1) == 0) z += zero ? 1 : 0;
    }
    int acc = p | (z << 16);
#pragma unroll
    for (int o = 1; o < 64; o <<= 1) acc += __shfl_xor(acc, o);
    int ps = acc & 0xffff, zs = acc >> 16;
    if (zs >= 100) return 0;
    return (ps >= 240) ? 1 : 0;
}

__device__ __forceinline__ short8 cvt8s(const float* p, float s) {
    float4 a = *(const float4*)p, b4 = *(const float4*)(p + 4);
    u32 r[4] = { pkbf(a.x * s, a.y * s), pkbf(a.z * s, a.w * s),
                 pkbf(b4.x * s, b4.y * s), pkbf(b4.z * s, b4.w * s) };
    return *(short8*)r;
}

__device__ __forceinline__ f32x16 zv16() {
    f32x16 z;
#pragma unroll
    for (int r = 0; r < 16; ++r) z[r] = 0.f;
    return z;
}

// Exchange a.hi-lanes <-> b.lo-lanes (v_permlane32_swap_b32 semantics).
__device__ __forceinline__ void plswap(u32& a, u32& b) {
#if __has_builtin(__builtin_amdgcn_permlane32_swap)
    auto r = __builtin_amdgcn_permlane32_swap(a, b, false, false);
    a = r[0]; b = r[1];
#else
    int lane = (int)(threadIdx.x & 63);
    u32 ax = (u32)__shfl_xor((int)a, 32);
    u32 bx = (u32)__shfl_xor((int)b, 32);
    bool hi = lane >= 32;
    u32 na = hi ? bx : a;
    u32 nb = hi ? b  : ax;
    a = na; b = nb;
#endif
}

// ---------------------------------------------------------------------------
// Fused full attention + l=0 local blend.
// Round-8 = round-7 resubmitted (round-7 bench was an infra failure; zero
// data collected). Round-5's 2-TILE-DEEP register prefetch pipeline made
// SPILL-FREE:
//   * two named prefetch sets A/B; iter kt issues loads for tile kt+2 while
//     computing tile kt; loads stay in flight across barrier+compute (~2x
//     window). Barriers are raw s_barrier + lgkmcnt(0) only -> in-flight
//     global loads cross barriers with a COUNTED vmcnt (from the STORE's
//     register dependence), never a full drain.
//   * in-place exp2 on St (R6-validated) kills the pe[16] transient: pays
//     for the B prefetch set. Row sums stay on f32 psum (1 reg; R6 showed
//     MFMA row-sums are dur-neutral, so spend regs on the pipeline).
// Geometry = round 3: 512 blocks x 512 thr, 128 q/block, KVBLK=64 shared
// double-buffered K/V tile, 32 iterations, 4 waves/SIMD.
// Wave w = (qg = w&3: 32-query sub-block) x (g = w>>2: key-half of tile).
// 32x32 MFMA; in-register P via cvt_pk+permlane32_swap; setprio on MFMA.
// Split-K halves combined through LDS at the end (exact, unnormalized).
// ---------------------------------------------------------------------------
template <int ISBF>
__device__ __forceinline__ void attn_impl(
    const void* __restrict__ qv, const void* __restrict__ kv,
    const void* __restrict__ vv, const void* __restrict__ alphav,
    void* __restrict__ outv, u16* SMEM)
{
    const int tid  = threadIdx.x;       // 0..511
    const int w    = tid >> 6;          // wave 0..7
    const int lane = tid & 63;
    const int l31  = lane & 31;
    const int hi   = lane >> 5;
    const int qg   = w & 3;             // query sub-block (32 rows)
    const int g    = w >> 2;            // key-half of each 64-key tile

    // XCD-aware mapping: xcd = fid&7 handles bh in {4*xcd .. 4*xcd+3}.
    const int fid = blockIdx.x;         // 0..511
    const int bh  = (fid & 7) * 4 + ((fid >> 3) & 3);
    const int rb  = fid >> 5;           // 0..15
    const int b   = bh >> 3, h = bh & 7;
    const int row0 = rb * 128;

    const size_t bhoff = (size_t)b * Lv * HE + h * Ev;
    const u16*   q16 = (const u16*)qv + bhoff;
    const u16*   k16 = (const u16*)kv + bhoff;
    const u16*   v16 = (const u16*)vv + bhoff;
    const float* q32 = (const float*)qv + bhoff;
    const float* k32 = (const float*)kv + bhoff;
    const float* v32 = (const float*)vv + bhoff;

    u16* Klds = SMEM;            // 2 bufs x 4096 u16  [key 0..63][e], swizzled
    u16* Vt   = SMEM + 8192;     // 2 bufs x 4096 u16  [e][key 0..63], swizzled

    // Q fragments (pre-scaled). B-operand of the 32x32 S^T MFMA:
    // qf[c][j] = Qs[row0+qg*32+l31][16c + 8hi + j].
    short8 qf[4];
    {
        size_t ro = (size_t)(row0 + qg * 32 + l31) * HE + hi * 8;
        if (ISBF) {
#pragma unroll
            for (int c = 0; c < 4; ++c) {
                short8 t = *(const short8*)(q16 + ro + 16 * c);
#pragma unroll
                for (int j = 0; j < 8; ++j)
                    qf[c][j] = (short)f2bf(bf2f((u16)t[j]) * QSCALE);
            }
        } else {
#pragma unroll
            for (int c = 0; c < 4; ++c) qf[c] = cvt8s(q32 + ro + 16 * c, QSCALE);
        }
    }

    f32x16 O[2];
    O[0] = zv16(); O[1] = zv16();
    float psum = 0.f;   // per-lane partial row sum (query l31, this g/hi slice)

    // K staging (512 threads, one 64-key tile): chunk tid: key=tid>>3,
    // slot=tid&7; XOR swizzle folded into GLOBAL offset, LDS write linear.
    const int kkey = tid >> 3, ksl = tid & 7;
    const int koff = kkey * HE + ((ksl ^ (kkey & 7)) * 8);
    // V staging: key-pair (2*pp, 2*pp+1), e-quad eq (4 e values).
    const int eq = tid & 15, pp = tid >> 4;      // pp 0..31
    const int kcv = pp >> 2, pq = pp & 3;

    // ---- two named prefetch register sets (rule #20: static names) ----
    float4 kfaA, kfbA, vfaA, vfbA, kfaB, kfbB, vfaB, vfbB;   // fp32 path
    uint4  kruA, kruB; uint2 vru0A, vru1A, vru0B, vru1B;     // bf16 path

#define LOAD_TILE(S, KT)                                                       \
    do {                                                                       \
        size_t kb_ = (size_t)(KT) * 64 * HE;                                   \
        if (ISBF) {                                                            \
            kru##S  = *(const uint4*)(k16 + kb_ + koff);                       \
            const u16* vp_ = v16 + kb_ + (size_t)(2 * pp) * HE + eq * 4;       \
            vru0##S = *(const uint2*)vp_;                                      \
            vru1##S = *(const uint2*)(vp_ + HE);                               \
        } else {                                                               \
            const float* kp_ = k32 + kb_ + koff;                               \
            kfa##S = *(const float4*)kp_;                                      \
            kfb##S = *(const float4*)(kp_ + 4);                                \
            const float* vp_ = v32 + kb_ + (size_t)(2 * pp) * HE + eq * 4;     \
            vfa##S = *(const float4*)vp_;                                      \
            vfb##S = *(const float4*)(vp_ + HE);                               \
        }                                                                      \
    } while (0)

#define STORE_TILE(S, KB, VB)                                                  \
    do {                                                                       \
        if (ISBF) {                                                            \
            *(uint4*)&(KB)[tid * 8] = kru##S;                                  \
            const u16* a0_ = (const u16*)&vru0##S;                             \
            const u16* a1_ = (const u16*)&vru1##S;                             \
            _Pragma("unroll")                                                  \
            for (int j = 0; j < 4; ++j) {                                      \
                int e_  = eq * 4 + j;                                          \
                int sl_ = kcv ^ ((e_ + (e_ >> 3)) & 7);                        \
                u32 val_ = (u32)a0_[j] | ((u32)a1_[j] << 16);                  \
                *(u32*)&(VB)[e_ * 64 + sl_ * 8 + pq * 2] = val_;               \
            }                                                                  \
        } else {                                                               \
            u32 kk_[4] = { pkbf(kfa##S.x, kfa##S.y), pkbf(kfa##S.z, kfa##S.w), \
                           pkbf(kfb##S.x, kfb##S.y), pkbf(kfb##S.z, kfb##S.w) };\
            *(uint4*)&(KB)[tid * 8] = *(uint4*)kk_;                            \
            float t0_[4] = {vfa##S.x, vfa##S.y, vfa##S.z, vfa##S.w};           \
            float t1_[4] = {vfb##S.x, vfb##S.y, vfb##S.z, vfb##S.w};           \
            _Pragma("unroll")                                                  \
            for (int j = 0; j < 4; ++j) {                                      \
                int e_  = eq * 4 + j;                                          \
                int sl_ = kcv ^ ((e_ + (e_ >> 3)) & 7);                        \
                *(u32*)&(VB)[e_ * 64 + sl_ * 8 + pq * 2] = pkbf(t0_[j], t1_[j]);\
            }                                                                  \
        }                                                                      \
    } while (0)

    // One K-iteration. SL = set receiving tile KT+2; SS = set holding tile
    // KT+1 (stored to LDS at the end of this iteration).
#define BODY(KT, SL, SS)                                                       \
    do {                                                                       \
        u16* Kb = Klds + ((KT) & 1) * 4096;                                    \
        u16* Vb = Vt   + ((KT) & 1) * 4096;                                    \
        if ((KT) < 30) LOAD_TILE(SL, (KT) + 2);                                \
        f32x16 St = zv16();                                                    \
        __builtin_amdgcn_s_setprio(1);                                         \
        _Pragma("unroll")                                                      \
        for (int c = 0; c < 4; ++c) {                                          \
            int sl = (2 * c + hi) ^ (l31 & 7);                                 \
            short8 kf = *(const short8*)&Kb[(g * 32 + l31) * 64 + sl * 8];     \
            St = MFMA32(kf, qf[c], St);                                        \
        }                                                                      \
        __builtin_amdgcn_s_setprio(0);                                         \
        _Pragma("unroll")                                                      \
        for (int r = 0; r < 16; ++r) St[r] = fexp2(St[r]);   /* in place */    \
        _Pragma("unroll")                                                      \
        for (int r = 0; r < 16; ++r) psum += St[r];                            \
        u32 c8[8];                                                             \
        _Pragma("unroll")                                                      \
        for (int q = 0; q < 8; ++q) c8[q] = pkbf(St[2 * q], St[2 * q + 1]);    \
        _Pragma("unroll")                                                      \
        for (int t = 0; t < 2; ++t) {                                          \
            u32 a0 = c8[4 * t + 0], a1 = c8[4 * t + 1];                        \
            u32 a2 = c8[4 * t + 2], a3 = c8[4 * t + 3];                        \
            plswap(a0, a2);                                                    \
            plswap(a1, a3);                                                    \
            u32 pw_[4] = { a0, a1, a2, a3 };                                   \
            short8 pa = *(short8*)pw_;                                         \
            int ks = 2 * g + t;                                                \
            __builtin_amdgcn_s_setprio(1);                                     \
            _Pragma("unroll")                                                  \
            for (int et = 0; et < 2; ++et) {                                   \
                int e  = et * 32 + l31;                                        \
                int sl = (2 * ks + hi) ^ ((e + (e >> 3)) & 7);                 \
                short8 vf = *(const short8*)&Vb[e * 64 + sl * 8];              \
                O[et] = MFMA32(pa, vf, O[et]);                                 \
            }                                                                  \
            __builtin_amdgcn_s_setprio(0);                                     \
        }                                                                      \
        if ((KT) < 31) {                                                       \
            u16* Kn = Klds + (((KT) + 1) & 1) * 4096;                          \
            u16* Vn = Vt   + (((KT) + 1) & 1) * 4096;                          \
            STORE_TILE(SS, Kn, Vn);                                            \
            asm volatile("s_waitcnt lgkmcnt(0)" ::: "memory");                 \
            __builtin_amdgcn_s_barrier();                                      \
        }                                                                      \
    } while (0)

    // ---- prologue: tile0 -> LDS buf0; tile1 loads left in flight in B ----
    LOAD_TILE(A, 0);
    LOAD_TILE(B, 1);
    STORE_TILE(A, Klds, Vt);    // compiler waits only the A-group (counted)
    asm volatile("s_waitcnt lgkmcnt(0)" ::: "memory");
    __builtin_amdgcn_s_barrier();

    // iter kt: LOAD(kt+2) -> set[kt&1]; compute buf[kt&1];
    //          STORE(set[(kt+1)&1] = tile kt+1) -> buf[(kt+1)&1]; barrier.
    for (int kt2 = 0; kt2 < 16; ++kt2) {
        const int kt = 2 * kt2;
        BODY(kt,     A, B);
        BODY(kt + 1, B, A);
    }
#undef LOAD_TILE
#undef STORE_TILE
#undef BODY

    // ---- combine the two key-halves through LDS (exact, unnormalized) ----
    __syncthreads();                              // all K/V tile reads done
    float pst = psum + __shfl_xor(psum, 32);      // row sum over this half
    float* cb = (float*)SMEM;                     // tiles dead; reuse as f32
    const int cbase = qg * 2368 + lane * 36;      // 36 f32 stride: 16B-aligned

    if (g == 1) {
        union { f32x16 v; float4 q4[4]; } u;
        u.v = O[0];
#pragma unroll
        for (int i = 0; i < 4; ++i) *(float4*)&cb[cbase + 4 * i] = u.q4[i];
        u.v = O[1];
#pragma unroll
        for (int i = 0; i < 4; ++i) *(float4*)&cb[cbase + 16 + 4 * i] = u.q4[i];
        cb[qg * 2368 + 2304 + lane] = pst;
    }

    // ---- l=0 local attention (wave 0 = qg0/g0 of rb==0 blocks) ----
    float locv[2] = {0.f, 0.f};
    float wgt = 0.f;
    const bool w0blk = (rb == 0) && (w == 0);
    if (w0blk) {
        const int e = lane;
        const size_t base = bhoff + e;
#define LDIN(p, i) (ISBF ? bf2f(((const u16*)(p))[i]) : ((const float*)(p))[i])
        float qe = LDIN(qv, base);
        float s[9];
#pragma unroll
        for (int j = 0; j < 9; ++j) {
            float prod = qe * LDIN(kv, base + (size_t)j * HE);
#pragma unroll
            for (int o = 1; o < 64; o <<= 1) prod += __shfl_xor(prod, o);
            s[j] = prod * 0.125f;
        }
        float mx = s[0];
#pragma unroll
        for (int j = 1; j < 9; ++j) mx = fmaxf(mx, s[j]);
        float we[9];
#pragma unroll
        for (int j = 0; j < 9; ++j) we[j] = expf(s[j] - mx);
        float denom = 9.f * we[0];
        float acc   = 9.f * we[0] * LDIN(vv, base);
#pragma unroll
        for (int j = 1; j < 9; ++j) {
            denom += we[j];
            acc   += we[j] * LDIN(vv, base + (size_t)j * HE);
        }
        float loc = acc / denom;

        float a;
        if (ISBF) {
            a = bf2f(((const u16*)alphav)[0]);
            if (!(a >= 0.0f && a <= 1.0f)) {
                float af = ((const float*)alphav)[0];
                if (af >= 0.0f && af <= 1.0f) a = af;
            }
        } else {
            a = ((const float*)alphav)[0];
            if (!(a >= 0.0f && a <= 1.0f)) {
                float ab = bf2f(((const u16*)alphav)[0]);
                if (ab >= 0.0f && ab <= 1.0f) a = ab;
            }
        }
        wgt = 1.f / (1.f + expf(-a));
#pragma unroll
        for (int et = 0; et < 2; ++et) locv[et] = __shfl(loc, et * 32 + l31);
#undef LDIN
    }

    __syncthreads();                              // partials visible
    if (g != 0) return;

    // ---- g==0 waves: add partner partials, normalize, blend, store ----
    float pstp = cb[qg * 2368 + 2304 + lane];
#pragma unroll
    for (int r = 0; r < 16; ++r) {
        O[0][r] += cb[cbase + r];
        O[1][r] += cb[cbase + 16 + r];
    }
    float invv = 1.0f / (pst + pstp);

#pragma unroll
    for (int rg = 0; rg < 4; ++rg) {
#pragma unroll
        for (int rr = 0; rr < 4; ++rr) {
            const int reg = rg * 4 + rr;
            const int rl  = rr + 8 * rg + 4 * hi;       // local output row
            float inv = __shfl(invv, rl);               // broadcast from lane rl
            int row = row0 + qg * 32 + rl;
            size_t oo = (size_t)(b * Lv + row) * HE + h * Ev + l31;
            bool blend = w0blk && (rl == 0);
#pragma unroll
            for (int et = 0; et < 2; ++et) {
                float res = O[et][reg] * inv;
                if (blend) res = wgt * res + (1.f - wgt) * locv[et];
                if (ISBF) ((u16*)outv)[oo + et * 32] = f2bf(res);
                else      ((float*)outv)[oo + et * 32] = res;
            }
        }
    }
}

__global__ __launch_bounds__(512, 4) void attn_kernel(
    const void* __restrict__ qv, const void* __restrict__ kv,
    const void* __restrict__ vv, const void* __restrict__ alphav,
    void* __restrict__ outv)
{
    // [0,8K) u16: K tiles (2 bufs x 64x64). [8K,16K) u16: V tiles (2 bufs).
    // Whole buffer reused as float scratch (9472 f32) for split-K combine.
    __shared__ u16 SMEM[18944];

    const int isbf = detect_isbf16((const u32*)qv, threadIdx.x & 63);
    if (isbf) attn_impl<1>(qv, kv, vv, alphav, outv, SMEM);
    else      attn_impl<0>(qv, kv, vv, alphav, outv, SMEM);
}

extern "C" void kernel_launch(void* const* d_in, const int* in_sizes, int n_in,
                              void* d_out, int out_size, void* d_ws, size_t ws_size,
                              hipStream_t stream) {
    hipLaunchKernelGGL(attn_kernel, dim3(512), dim3(512), 0, stream,
                       d_in[0], d_in[1], d_in[2], d_in[3], d_out);
}